// Round 6
// baseline (854.994 us; speedup 1.0000x reference)
//
#include <hip/hip_runtime.h>
#include <hip/hip_bf16.h>

#define BATCH 64
#define L 1024
#define DIM 640
#define INNER 256
#define OUTER 1024
#define QKW 512   // fused Q|K projection width

typedef __attribute__((ext_vector_type(8))) short bf16x8;
typedef __attribute__((ext_vector_type(4))) float f32x4;

__device__ __forceinline__ float bf2f(unsigned short u) {
    union { unsigned int i; float f; } v; v.i = ((unsigned int)u) << 16; return v.f;
}
__device__ __forceinline__ unsigned short f2bf(float f) {
    __hip_bfloat16 h = __float2bfloat16(f);
    return *reinterpret_cast<unsigned short*>(&h);
}
__device__ __forceinline__ void gload_lds16(const void* g, void* l) {
    __builtin_amdgcn_global_load_lds(
        (const __attribute__((address_space(1))) void*)g,
        (__attribute__((address_space(3))) void*)l, 16, 0, 0);
}

// ---------------------------------------------------------------------------
// Wt[512][640] bf16 = concat(Wq^T, Wk^T)
// ---------------------------------------------------------------------------
__global__ __launch_bounds__(256)
void wt_kernel(const float* __restrict__ Wq, const float* __restrict__ Wk,
               unsigned short* __restrict__ Wt)
{
    int idx = blockIdx.x * 256 + threadIdx.x;
    if (idx >= QKW * DIM) return;
    int n = idx / DIM, k = idx - n * DIM;
    float v = (n < INNER) ? Wq[(size_t)k * INNER + n]
                          : Wk[(size_t)k * INNER + (n - INNER)];
    Wt[idx] = f2bf(v);
}

// ---------------------------------------------------------------------------
// Fused cvt + Q|K projection: Y[M][512] = bf16(X_f32[M][640]) @ Wt^T + (bq|bk)
// BK=64, double-buffered, 2-phase pipeline. A: reg-staged f32->bf16 with
// XOR-swizzled ds_write; B: global_load_lds with inverse-swizzled source.
// Tiles [128][64] bf16, swizzle: LDS 16B-chunk c of row r holds global chunk
// c ^ (r&7)  (involution; ds_read applies the same XOR).
// 1D grid 2048 blocks, XCD-chunked, n-fast (A-tile L2 reuse). Skips m-tiles
// beyond ceil128(len[batch]).
// ---------------------------------------------------------------------------
__global__ __launch_bounds__(256)
void projqk_kernel(const float* __restrict__ X,
                   const unsigned short* __restrict__ Wt,
                   const float* __restrict__ bq, const float* __restrict__ bk,
                   const int* __restrict__ len,
                   unsigned short* __restrict__ Y)
{
    __shared__ unsigned short As[2][8192];   // [128][64] bf16, swizzled
    __shared__ unsigned short Bs[2][8192];
    const int bid = blockIdx.x;                 // 2048 = 8 XCD * 256
    const int xcd = bid & 7, idx = bid >> 3;
    const int widx = xcd * 256 + idx;
    const int nt = widx & 3, mt = widx >> 2;    // mt 0..511, n-fast
    const int batch = mt >> 3, mloc = mt & 7;
    if (mloc * 128 >= len[batch]) return;

    const int tid = threadIdx.x;
    const int w = tid >> 6, l = tid & 63;
    const int bm = mt * 128, bn = nt * 128;
    const int wr = w >> 1, wc = w & 1;
    const int swz = ((l & 7) ^ ((l >> 3) & 7)) * 8;   // inverse-swizzled src chunk

    // B staging: global_load_lds, linear dest, swizzled source
    const unsigned short* Bg = Wt + (size_t)(bn + w*8 + (l>>3)) * DIM + swz;
    // A: reg-staged, 2 threads/row, 32 f32 each
    const int ar = tid >> 1, ah = tid & 1;
    const float* Ax = X + (size_t)(bm + ar) * DIM + ah * 32;

    auto STAGE_B = [&](int buf, int k0) {
        #pragma unroll
        for (int i = 0; i < 4; ++i)
            gload_lds16(Bg + (size_t)(i*32) * DIM + k0, &Bs[buf][w*512 + i*2048]);
    };
    auto LOAD_A = [&](float4* d, int k0) {
        #pragma unroll
        for (int j = 0; j < 8; ++j) d[j] = *(const float4*)(Ax + k0 + j*4);
    };
    auto WRITE_A = [&](int buf, const float4* s) {
        #pragma unroll
        for (int j = 0; j < 4; ++j) {
            union { bf16x8 v; unsigned short u[8]; } pk;
            float4 x = s[2*j], y = s[2*j+1];
            pk.u[0]=f2bf(x.x); pk.u[1]=f2bf(x.y); pk.u[2]=f2bf(x.z); pk.u[3]=f2bf(x.w);
            pk.u[4]=f2bf(y.x); pk.u[5]=f2bf(y.y); pk.u[6]=f2bf(y.z); pk.u[7]=f2bf(y.w);
            *(bf16x8*)&As[buf][ar*64 + (((ah*4 + j) ^ (ar & 7)) * 8)] = pk.v;
        }
    };

    f32x4 acc[4][4] = {};
    auto COMPUTE = [&](int buf) {
        #pragma unroll
        for (int kk2 = 0; kk2 < 2; ++kk2) {
            const int slot = ((kk2*4 + (l>>4)) ^ (l & 7)) * 8;
            bf16x8 af[4], bfr[4];
            #pragma unroll
            for (int m = 0; m < 4; ++m)
                af[m] = *(const bf16x8*)&As[buf][(wr*64 + m*16 + (l&15))*64 + slot];
            #pragma unroll
            for (int n = 0; n < 4; ++n)
                bfr[n] = *(const bf16x8*)&Bs[buf][(wc*64 + n*16 + (l&15))*64 + slot];
            #pragma unroll
            for (int m = 0; m < 4; ++m)
                #pragma unroll
                for (int n = 0; n < 4; ++n)
                    acc[m][n] = __builtin_amdgcn_mfma_f32_16x16x32_bf16(af[m], bfr[n], acc[m][n], 0, 0, 0);
        }
    };

    float4 va0[8], va1[8];
    LOAD_A(va0, 0);
    STAGE_B(0, 0);
    WRITE_A(0, va0);
    __syncthreads();

    // 10 trips (DIM/64), unrolled in pairs for static reg-buffer indices
    #pragma unroll
    for (int t = 0; t < 10; t += 2) {
        if (t + 1 < 10) { LOAD_A(va1, (t+1)*64); STAGE_B(1, (t+1)*64); }
        COMPUTE(0);
        if (t + 1 < 10) WRITE_A(1, va1);
        __syncthreads();
        if (t + 1 < 10) {
            if (t + 2 < 10) { LOAD_A(va0, (t+2)*64); STAGE_B(0, (t+2)*64); }
            COMPUTE(1);
            if (t + 2 < 10) WRITE_A(0, va0);
            __syncthreads();
        }
    }

    #pragma unroll
    for (int m = 0; m < 4; ++m)
        #pragma unroll
        for (int n = 0; n < 4; ++n) {
            const int col = bn + wc*64 + n*16 + (l&15);
            const float bias = (col < INNER) ? bq[col] : bk[col - INNER];
            #pragma unroll
            for (int j = 0; j < 4; ++j) {
                const int row = bm + wr*64 + m*16 + (l>>4)*4 + j;
                Y[(size_t)row * QKW + col] = f2bf(acc[m][n][j] + bias);
            }
        }
}

// ---------------------------------------------------------------------------
// Scores: S = Q@K^T / 16, masked exp -> E (bf16), row sums -> lsum (atomic).
// BK=64, double-buffered 2-phase, both tiles via global_load_lds with
// inverse-swizzled source + swizzled ds_read. Early-exit on masked tiles.
// ---------------------------------------------------------------------------
__global__ __launch_bounds__(256)
void scores_kernel(const unsigned short* __restrict__ QKq,
                   const unsigned short* __restrict__ QKk,
                   const int* __restrict__ len_q,
                   const int* __restrict__ len_k,
                   unsigned short* __restrict__ E,
                   float* __restrict__ lsum, int b0)
{
    __shared__ unsigned short As[2][8192];   // Q tile [128][64] swizzled
    __shared__ unsigned short Bs[2][8192];   // K tile
    const int bz = blockIdx.z, b = b0 + bz;
    const int bm = blockIdx.x * 128, bn = blockIdx.y * 128;
    const int lq = len_q[b], lenk = len_k[b];
    if (bm >= lq || bn >= lenk) return;

    const int tid = threadIdx.x;
    const int w = tid >> 6, l = tid & 63;
    const int wr = w >> 1, wc = w & 1;
    const int swz = ((l & 7) ^ ((l >> 3) & 7)) * 8;

    const unsigned short* Qg = QKq + ((size_t)b * L + bm + w*8 + (l>>3)) * QKW + swz;
    const unsigned short* Kg = QKk + ((size_t)b * L + bn + w*8 + (l>>3)) * QKW + INNER + swz;

    auto STAGE = [&](int buf, int k0) {
        #pragma unroll
        for (int i = 0; i < 4; ++i) {
            gload_lds16(Qg + (size_t)(i*32) * QKW + k0, &As[buf][w*512 + i*2048]);
            gload_lds16(Kg + (size_t)(i*32) * QKW + k0, &Bs[buf][w*512 + i*2048]);
        }
    };

    f32x4 acc[4][4] = {};
    auto COMPUTE = [&](int buf) {
        #pragma unroll
        for (int kk2 = 0; kk2 < 2; ++kk2) {
            const int slot = ((kk2*4 + (l>>4)) ^ (l & 7)) * 8;
            bf16x8 af[4], bfr[4];
            #pragma unroll
            for (int m = 0; m < 4; ++m)
                af[m] = *(const bf16x8*)&As[buf][(wr*64 + m*16 + (l&15))*64 + slot];
            #pragma unroll
            for (int n = 0; n < 4; ++n)
                bfr[n] = *(const bf16x8*)&Bs[buf][(wc*64 + n*16 + (l&15))*64 + slot];
            #pragma unroll
            for (int m = 0; m < 4; ++m)
                #pragma unroll
                for (int n = 0; n < 4; ++n)
                    acc[m][n] = __builtin_amdgcn_mfma_f32_16x16x32_bf16(af[m], bfr[n], acc[m][n], 0, 0, 0);
        }
    };

    STAGE(0, 0);
    __syncthreads();
    #pragma unroll
    for (int t = 0; t < 4; ++t) {          // INNER/64
        if (t < 3) STAGE((t+1) & 1, (t+1)*64);
        COMPUTE(t & 1);
        __syncthreads();
    }

    const float scale = 0.0625f;   // 1/sqrt(256)
    float rs[4][4];
    #pragma unroll
    for (int m = 0; m < 4; ++m)
        #pragma unroll
        for (int j = 0; j < 4; ++j) rs[m][j] = 0.f;

    #pragma unroll
    for (int m = 0; m < 4; ++m)
        #pragma unroll
        for (int n = 0; n < 4; ++n) {
            const int col = bn + wc*64 + n*16 + (l&15);
            const bool valid = col < lenk;
            #pragma unroll
            for (int j = 0; j < 4; ++j) {
                const float e = valid ? __expf(acc[m][n][j] * scale) : 0.f;
                rs[m][j] += e;
                const int row = bm + wr*64 + m*16 + (l>>4)*4 + j;
                E[((size_t)bz * L + row) * L + col] = f2bf(e);
            }
        }

    #pragma unroll
    for (int m = 0; m < 4; ++m)
        #pragma unroll
        for (int j = 0; j < 4; ++j) {
            float v = rs[m][j];
            v += __shfl_xor(v, 1); v += __shfl_xor(v, 2);
            v += __shfl_xor(v, 4); v += __shfl_xor(v, 8);
            if ((l & 15) == 0) {
                const int row = bm + wr*64 + m*16 + (l>>4)*4 + j;
                atomicAdd(&lsum[(size_t)b * L + row], v);
            }
        }
}

// ---------------------------------------------------------------------------
// w[b][k] = (1/len_q) * sum_{q<len_q} E[q][k] / lsum[q]
// ---------------------------------------------------------------------------
__global__ __launch_bounds__(256)
void colsum_kernel(const unsigned short* __restrict__ E, const float* __restrict__ lsum,
                   const int* __restrict__ len_q, const int* __restrict__ len_k,
                   float* __restrict__ w, int b0)
{
    const int bz = blockIdx.y, b = b0 + bz;
    const int qc = blockIdx.x * 128;
    const int lq = len_q[b];
    if (qc >= lq) return;
    const int k4 = threadIdx.x * 4;
    if (k4 >= len_k[b]) return;
    const int qe = (qc + 128 < lq) ? qc + 128 : lq;
    const unsigned short* Eb = E + (size_t)bz * L * L + k4;
    const float* lb = lsum + (size_t)b * L;
    const float inv_lq = 1.0f / (float)lq;
    float a0 = 0.f, a1 = 0.f, a2 = 0.f, a3 = 0.f;
    for (int q = qc; q < qe; ++q) {
        ushort4 ev = *(const ushort4*)(Eb + (size_t)q * L);
        float r = inv_lq / lb[q];
        a0 += bf2f(ev.x) * r; a1 += bf2f(ev.y) * r;
        a2 += bf2f(ev.z) * r; a3 += bf2f(ev.w) * r;
    }
    float* wb = w + (size_t)b * L + k4;
    atomicAdd(wb + 0, a0); atomicAdd(wb + 1, a1);
    atomicAdd(wb + 2, a2); atomicAdd(wb + 3, a3);
}

// ---------------------------------------------------------------------------
// pooled[b][d] = sum_k w[b][k] * X[b][k][d]   (f32 exact V path)
// ---------------------------------------------------------------------------
__global__ __launch_bounds__(256)
void pool_kernel(const float* __restrict__ w, const float* __restrict__ X,
                 float* __restrict__ pooled)
{
    const int b   = blockIdx.y;
    const int kc  = blockIdx.x * 128;
    const int tid = threadIdx.x;
    const float* wb = w + (size_t)b * L + kc;
    const float* Xb = X + ((size_t)b * L + kc) * DIM;
    float acc0 = 0.f, acc1 = 0.f, acc2 = 0.f;
    for (int kk = 0; kk < 128; ++kk) {
        float wgt = wb[kk];
        if (wgt == 0.f) continue;   // masked keys: exact zero, uniform branch
        const float* row = Xb + (size_t)kk * DIM;
        acc0 += wgt * row[tid];
        acc1 += wgt * row[tid + 256];
        if (tid < 128) acc2 += wgt * row[tid + 512];
    }
    atomicAdd(&pooled[(size_t)b * DIM + tid],       acc0);
    atomicAdd(&pooled[(size_t)b * DIM + tid + 256], acc1);
    if (tid < 128) atomicAdd(&pooled[(size_t)b * DIM + tid + 512], acc2);
}

// ---------------------------------------------------------------------------
// out[r][o] = pooled[r][:] @ Wv[:,o] + bv[o]
// ---------------------------------------------------------------------------
__global__ __launch_bounds__(256)
void outproj_kernel(const float* __restrict__ pooled, const float* __restrict__ Wv,
                    const float* __restrict__ bv, float* __restrict__ out)
{
    const int r = blockIdx.x;
    const int o = blockIdx.y * 256 + threadIdx.x;
    const float* p = pooled + (size_t)r * DIM;
    float a0 = bv[o], a1 = 0.f, a2 = 0.f, a3 = 0.f;
    for (int d = 0; d < DIM; d += 4) {
        a0 = fmaf(p[d+0], Wv[(size_t)(d+0)*OUTER + o], a0);
        a1 = fmaf(p[d+1], Wv[(size_t)(d+1)*OUTER + o], a1);
        a2 = fmaf(p[d+2], Wv[(size_t)(d+2)*OUTER + o], a2);
        a3 = fmaf(p[d+3], Wv[(size_t)(d+3)*OUTER + o], a3);
    }
    out[(size_t)r * OUTER + o] = (a0+a1)+(a2+a3);
}

// ---------------------------------------------------------------------------
extern "C" void kernel_launch(void* const* d_in, const int* in_sizes, int n_in,
                              void* d_out, int out_size, void* d_ws, size_t ws_size,
                              hipStream_t stream)
{
    (void)in_sizes; (void)n_in; (void)out_size;
    const float* a_pad = (const float*)d_in[0];
    const float* b_pad = (const float*)d_in[1];
    const int*   len_a = (const int*)d_in[2];
    const int*   len_b = (const int*)d_in[3];
    const float* Wq    = (const float*)d_in[4];
    const float* bq    = (const float*)d_in[5];
    const float* Wk    = (const float*)d_in[6];
    const float* bk    = (const float*)d_in[7];
    const float* Wv    = (const float*)d_in[8];
    const float* bv    = (const float*)d_in[9];
    float* out = (float*)d_out;

    char* ws = (char*)d_ws;
    size_t off = 0;
    auto alloc = [&](size_t bytes) -> void* {
        void* p = (void*)(ws + off);
        off += (bytes + 255) & ~(size_t)255;
        return p;
    };

    const size_t QE = (size_t)BATCH * L * QKW;
    unsigned short* Wt  = (unsigned short*)alloc((size_t)QKW * DIM * 2);
    unsigned short* QKa = (unsigned short*)alloc(QE * 2);
    unsigned short* QKb = (unsigned short*)alloc(QE * 2);
    float* l2     = (float*)alloc((size_t)2 * BATCH * L * 4);
    float* w2     = (float*)alloc((size_t)2 * BATCH * L * 4);
    float* pooled = (float*)alloc((size_t)2 * BATCH * DIM * 4);
    unsigned short* E = (unsigned short*)(ws + off);
    size_t eAvail = (ws_size > off) ? (ws_size - off) : 0;
    int gb = (int)(eAvail / ((size_t)L * L * 2));
    if (gb < 1) gb = 1;
    if (gb > BATCH) gb = BATCH;

    wt_kernel<<<(QKW * DIM + 255) / 256, 256, 0, stream>>>(Wq, Wk, Wt);

    projqk_kernel<<<2048, 256, 0, stream>>>(a_pad, Wt, bq, bk, len_a, QKa);
    projqk_kernel<<<2048, 256, 0, stream>>>(b_pad, Wt, bq, bk, len_b, QKb);

    hipMemsetAsync(l2,     0, (size_t)2 * BATCH * L * 4,   stream);
    hipMemsetAsync(w2,     0, (size_t)2 * BATCH * L * 4,   stream);
    hipMemsetAsync(pooled, 0, (size_t)2 * BATCH * DIM * 4, stream);

    for (int dir = 0; dir < 2; ++dir) {
        const unsigned short* QKq = (dir == 0) ? QKa : QKb;
        const unsigned short* QKk = (dir == 0) ? QKb : QKa;
        const int* lenq = (dir == 0) ? len_a : len_b;
        const int* lenk = (dir == 0) ? len_b : len_a;
        float* lsum = l2 + (size_t)dir * BATCH * L;
        float* wv   = w2 + (size_t)dir * BATCH * L;
        for (int b0 = 0; b0 < BATCH; b0 += gb) {
            int g = (gb < BATCH - b0) ? gb : (BATCH - b0);
            scores_kernel<<<dim3(8, 8, g), 256, 0, stream>>>(QKq, QKk, lenq, lenk, E, lsum, b0);
            colsum_kernel<<<dim3(8, g), 256, 0, stream>>>(E, lsum, lenq, lenk, wv, b0);
        }
    }

    pool_kernel<<<dim3(8, BATCH), 256, 0, stream>>>(w2,                   b_pad, pooled);
    pool_kernel<<<dim3(8, BATCH), 256, 0, stream>>>(w2 + (size_t)BATCH*L, a_pad, pooled + (size_t)BATCH*DIM);
    outproj_kernel<<<dim3(128, 4), 256, 0, stream>>>(pooled, Wv, bv, out);
}

// Round 8
// 814.818 us; speedup vs baseline: 1.0493x; 1.0493x over previous
//
#include <hip/hip_runtime.h>
#include <hip/hip_bf16.h>

#define BATCH 64
#define L 1024
#define DIM 640
#define INNER 256
#define OUTER 1024
#define QKW 512   // fused Q|K projection width

typedef __attribute__((ext_vector_type(8))) short bf16x8;
typedef __attribute__((ext_vector_type(4))) float f32x4;

__device__ __forceinline__ float bf2f(unsigned short u) {
    union { unsigned int i; float f; } v; v.i = ((unsigned int)u) << 16; return v.f;
}
__device__ __forceinline__ unsigned short f2bf(float f) {
    __hip_bfloat16 h = __float2bfloat16(f);
    return *reinterpret_cast<unsigned short*>(&h);
}
__device__ __forceinline__ void gload_lds16(const void* g, void* l) {
    __builtin_amdgcn_global_load_lds(
        (const __attribute__((address_space(1))) void*)g,
        (__attribute__((address_space(3))) void*)l, 16, 0, 0);
}

// ---------------------------------------------------------------------------
// Wt[512][640] bf16 = concat(Wq^T, Wk^T)
// ---------------------------------------------------------------------------
__global__ __launch_bounds__(256)
void wt_kernel(const float* __restrict__ Wq, const float* __restrict__ Wk,
               unsigned short* __restrict__ Wt)
{
    int idx = blockIdx.x * 256 + threadIdx.x;
    if (idx >= QKW * DIM) return;
    int n = idx / DIM, k = idx - n * DIM;
    float v = (n < INNER) ? Wq[(size_t)k * INNER + n]
                          : Wk[(size_t)k * INNER + (n - INNER)];
    Wt[idx] = f2bf(v);
}

// ---------------------------------------------------------------------------
// Fused cvt + Q|K projection: Y[M][512] = bf16(X_f32[M][640]) @ Wt^T + (bq|bk)
// 512 threads / 8 waves (2x4), per-wave 64x32 output, BK=64 double-buffered.
// A: reg-staged f32->bf16, XOR-swizzled ds_write; B: global_load_lds with
// inverse-swizzled source. Swizzle: 16B chunk c of row r <-> c ^ (r&7).
// ---------------------------------------------------------------------------
__global__ __launch_bounds__(512)
void projqk_kernel(const float* __restrict__ X,
                   const unsigned short* __restrict__ Wt,
                   const float* __restrict__ bq, const float* __restrict__ bk,
                   const int* __restrict__ len,
                   unsigned short* __restrict__ Y)
{
    __shared__ unsigned short As[2][8192];   // [128][64] bf16, swizzled
    __shared__ unsigned short Bs[2][8192];
    const int bid = blockIdx.x;                 // 2048 = 8 XCD * 256
    const int xcd = bid & 7, idx = bid >> 3;
    const int widx = xcd * 256 + idx;
    const int nt = widx & 3, mt = widx >> 2;    // mt 0..511, n-fast
    const int batch = mt >> 3, mloc = mt & 7;
    if (mloc * 128 >= len[batch]) return;

    const int tid = threadIdx.x;
    const int w = tid >> 6, l = tid & 63;
    const int bm = mt * 128, bn = nt * 128;
    const int wr = w >> 2, wc = w & 3;          // 2x4 wave grid
    const int swz = ((l & 7) ^ ((l >> 3) & 7)) * 8;

    // B: wave w, issue i covers rows w*16+i*8+(l>>3), chunkcol l&7 (linear dest)
    const unsigned short* Bg = Wt + (size_t)(bn + w*16 + (l>>3)) * DIM + swz;
    // A: 1 thread per quarter-row: 16 f32
    const int ar = tid >> 2, aq = tid & 3;
    const float* Ax = X + (size_t)(bm + ar) * DIM + aq * 16;

    auto STAGE_B = [&](int buf, int k0) {
        #pragma unroll
        for (int i = 0; i < 2; ++i)
            gload_lds16(Bg + (size_t)(i*8) * DIM + k0, &Bs[buf][w*1024 + i*512]);
    };
    auto LOAD_A = [&](float4* d, int k0) {
        #pragma unroll
        for (int j = 0; j < 4; ++j) d[j] = *(const float4*)(Ax + k0 + j*4);
    };
    auto WRITE_A = [&](int buf, const float4* s) {
        #pragma unroll
        for (int j = 0; j < 2; ++j) {
            union { bf16x8 v; unsigned short u[8]; } pk;
            float4 x = s[2*j], y = s[2*j+1];
            pk.u[0]=f2bf(x.x); pk.u[1]=f2bf(x.y); pk.u[2]=f2bf(x.z); pk.u[3]=f2bf(x.w);
            pk.u[4]=f2bf(y.x); pk.u[5]=f2bf(y.y); pk.u[6]=f2bf(y.z); pk.u[7]=f2bf(y.w);
            *(bf16x8*)&As[buf][ar*64 + (((aq*2 + j) ^ (ar & 7)) * 8)] = pk.v;
        }
    };

    f32x4 acc[4][2] = {};
    auto COMPUTE = [&](int buf) {
        #pragma unroll
        for (int kk2 = 0; kk2 < 2; ++kk2) {
            const int slot = ((kk2*4 + (l>>4)) ^ (l & 7)) * 8;
            bf16x8 af[4], bfr[2];
            #pragma unroll
            for (int m = 0; m < 4; ++m)
                af[m] = *(const bf16x8*)&As[buf][(wr*64 + m*16 + (l&15))*64 + slot];
            #pragma unroll
            for (int n = 0; n < 2; ++n)
                bfr[n] = *(const bf16x8*)&Bs[buf][(wc*32 + n*16 + (l&15))*64 + slot];
            #pragma unroll
            for (int m = 0; m < 4; ++m)
                #pragma unroll
                for (int n = 0; n < 2; ++n)
                    acc[m][n] = __builtin_amdgcn_mfma_f32_16x16x32_bf16(af[m], bfr[n], acc[m][n], 0, 0, 0);
        }
    };

    float4 va0[4], va1[4];
    LOAD_A(va0, 0);
    STAGE_B(0, 0);
    WRITE_A(0, va0);
    __syncthreads();

    // 10 trips (DIM/64), unrolled in pairs for static reg-buffer indices
    #pragma unroll
    for (int t = 0; t < 10; t += 2) {
        if (t + 1 < 10) { LOAD_A(va1, (t+1)*64); STAGE_B(1, (t+1)*64); }
        COMPUTE(0);
        if (t + 1 < 10) WRITE_A(1, va1);
        __syncthreads();
        if (t + 1 < 10) {
            if (t + 2 < 10) { LOAD_A(va0, (t+2)*64); STAGE_B(0, (t+2)*64); }
            COMPUTE(1);
            if (t + 2 < 10) WRITE_A(0, va0);
            __syncthreads();
        }
    }

    #pragma unroll
    for (int m = 0; m < 4; ++m)
        #pragma unroll
        for (int n = 0; n < 2; ++n) {
            const int col = bn + wc*32 + n*16 + (l&15);
            const float bias = (col < INNER) ? bq[col] : bk[col - INNER];
            #pragma unroll
            for (int j = 0; j < 4; ++j) {
                const int row = bm + wr*64 + m*16 + (l>>4)*4 + j;
                Y[(size_t)row * QKW + col] = f2bf(acc[m][n][j] + bias);
            }
        }
}

// ---------------------------------------------------------------------------
// Scores: S = Q@K^T / 16, masked exp -> E (bf16), row sums -> lsum (atomic).
// 512 threads / 8 waves (2x4), BK=64 double-buffered, both tiles via
// global_load_lds with inverse-swizzled source + swizzled ds_read.
// ---------------------------------------------------------------------------
__global__ __launch_bounds__(512)
void scores_kernel(const unsigned short* __restrict__ QKq,
                   const unsigned short* __restrict__ QKk,
                   const int* __restrict__ len_q,
                   const int* __restrict__ len_k,
                   unsigned short* __restrict__ E,
                   float* __restrict__ lsum, int b0)
{
    __shared__ unsigned short As[2][8192];   // Q tile [128][64] swizzled
    __shared__ unsigned short Bs[2][8192];   // K tile
    const int bz = blockIdx.z, b = b0 + bz;
    const int bm = blockIdx.x * 128, bn = blockIdx.y * 128;
    const int lq = len_q[b], lenk = len_k[b];
    if (bm >= lq || bn >= lenk) return;

    const int tid = threadIdx.x;
    const int w = tid >> 6, l = tid & 63;
    const int wr = w >> 2, wc = w & 3;
    const int swz = ((l & 7) ^ ((l >> 3) & 7)) * 8;

    const unsigned short* Qg = QKq + ((size_t)b * L + bm + w*16 + (l>>3)) * QKW + swz;
    const unsigned short* Kg = QKk + ((size_t)b * L + bn + w*16 + (l>>3)) * QKW + INNER + swz;

    auto STAGE = [&](int buf, int k0) {
        #pragma unroll
        for (int i = 0; i < 2; ++i) {
            gload_lds16(Qg + (size_t)(i*8) * QKW + k0, &As[buf][w*1024 + i*512]);
            gload_lds16(Kg + (size_t)(i*8) * QKW + k0, &Bs[buf][w*1024 + i*512]);
        }
    };

    f32x4 acc[4][2] = {};
    auto COMPUTE = [&](int buf) {
        #pragma unroll
        for (int kk2 = 0; kk2 < 2; ++kk2) {
            const int slot = ((kk2*4 + (l>>4)) ^ (l & 7)) * 8;
            bf16x8 af[4], bfr[2];
            #pragma unroll
            for (int m = 0; m < 4; ++m)
                af[m] = *(const bf16x8*)&As[buf][(wr*64 + m*16 + (l&15))*64 + slot];
            #pragma unroll
            for (int n = 0; n < 2; ++n)
                bfr[n] = *(const bf16x8*)&Bs[buf][(wc*32 + n*16 + (l&15))*64 + slot];
            #pragma unroll
            for (int m = 0; m < 4; ++m)
                #pragma unroll
                for (int n = 0; n < 2; ++n)
                    acc[m][n] = __builtin_amdgcn_mfma_f32_16x16x32_bf16(af[m], bfr[n], acc[m][n], 0, 0, 0);
        }
    };

    STAGE(0, 0);
    __syncthreads();
    #pragma unroll
    for (int t = 0; t < 4; ++t) {          // INNER/64
        if (t < 3) STAGE((t+1) & 1, (t+1)*64);
        COMPUTE(t & 1);
        __syncthreads();
    }

    const float scale = 0.0625f;   // 1/sqrt(256)
    float rs[4][4];
    #pragma unroll
    for (int m = 0; m < 4; ++m)
        #pragma unroll
        for (int j = 0; j < 4; ++j) rs[m][j] = 0.f;

    #pragma unroll
    for (int m = 0; m < 4; ++m)
        #pragma unroll
        for (int n = 0; n < 2; ++n) {
            const int col = bn + wc*32 + n*16 + (l&15);
            const bool valid = col < lenk;
            #pragma unroll
            for (int j = 0; j < 4; ++j) {
                const float e = valid ? __expf(acc[m][n][j] * scale) : 0.f;
                rs[m][j] += e;
                const int row = bm + wr*64 + m*16 + (l>>4)*4 + j;
                E[((size_t)bz * L + row) * L + col] = f2bf(e);
            }
        }

    #pragma unroll
    for (int m = 0; m < 4; ++m)
        #pragma unroll
        for (int j = 0; j < 4; ++j) {
            float v = rs[m][j];
            v += __shfl_xor(v, 1); v += __shfl_xor(v, 2);
            v += __shfl_xor(v, 4); v += __shfl_xor(v, 8);
            if ((l & 15) == 0) {
                const int row = bm + wr*64 + m*16 + (l>>4)*4 + j;
                atomicAdd(&lsum[(size_t)b * L + row], v);
            }
        }
}

// ---------------------------------------------------------------------------
// w[b][k] = (1/len_q) * sum_{q<len_q} E[q][k] / lsum[q]
// ---------------------------------------------------------------------------
__global__ __launch_bounds__(256)
void colsum_kernel(const unsigned short* __restrict__ E, const float* __restrict__ lsum,
                   const int* __restrict__ len_q, const int* __restrict__ len_k,
                   float* __restrict__ w, int b0)
{
    const int bz = blockIdx.y, b = b0 + bz;
    const int qc = blockIdx.x * 128;
    const int lq = len_q[b];
    if (qc >= lq) return;
    const int k4 = threadIdx.x * 4;
    if (k4 >= len_k[b]) return;
    const int qe = (qc + 128 < lq) ? qc + 128 : lq;
    const unsigned short* Eb = E + (size_t)bz * L * L + k4;
    const float* lb = lsum + (size_t)b * L;
    const float inv_lq = 1.0f / (float)lq;
    float a0 = 0.f, a1 = 0.f, a2 = 0.f, a3 = 0.f;
    for (int q = qc; q < qe; ++q) {
        ushort4 ev = *(const ushort4*)(Eb + (size_t)q * L);
        float r = inv_lq / lb[q];
        a0 += bf2f(ev.x) * r; a1 += bf2f(ev.y) * r;
        a2 += bf2f(ev.z) * r; a3 += bf2f(ev.w) * r;
    }
    float* wb = w + (size_t)b * L + k4;
    atomicAdd(wb + 0, a0); atomicAdd(wb + 1, a1);
    atomicAdd(wb + 2, a2); atomicAdd(wb + 3, a3);
}

// ---------------------------------------------------------------------------
// pooled[b][d] = sum_k w[b][k] * X[b][k][d]   (f32 exact V path)
// ---------------------------------------------------------------------------
__global__ __launch_bounds__(256)
void pool_kernel(const float* __restrict__ w, const float* __restrict__ X,
                 float* __restrict__ pooled)
{
    const int b   = blockIdx.y;
    const int kc  = blockIdx.x * 128;
    const int tid = threadIdx.x;
    const float* wb = w + (size_t)b * L + kc;
    const float* Xb = X + ((size_t)b * L + kc) * DIM;
    float acc0 = 0.f, acc1 = 0.f, acc2 = 0.f;
    for (int kk = 0; kk < 128; ++kk) {
        float wgt = wb[kk];
        if (wgt == 0.f) continue;   // masked keys: exact zero, uniform branch
        const float* row = Xb + (size_t)kk * DIM;
        acc0 += wgt * row[tid];
        acc1 += wgt * row[tid + 256];
        if (tid < 128) acc2 += wgt * row[tid + 512];
    }
    atomicAdd(&pooled[(size_t)b * DIM + tid],       acc0);
    atomicAdd(&pooled[(size_t)b * DIM + tid + 256], acc1);
    if (tid < 128) atomicAdd(&pooled[(size_t)b * DIM + tid + 512], acc2);
}

// ---------------------------------------------------------------------------
// out[r][o] = pooled[r][:] @ Wv[:,o] + bv[o]
// ---------------------------------------------------------------------------
__global__ __launch_bounds__(256)
void outproj_kernel(const float* __restrict__ pooled, const float* __restrict__ Wv,
                    const float* __restrict__ bv, float* __restrict__ out)
{
    const int r = blockIdx.x;
    const int o = blockIdx.y * 256 + threadIdx.x;
    const float* p = pooled + (size_t)r * DIM;
    float a0 = bv[o], a1 = 0.f, a2 = 0.f, a3 = 0.f;
    for (int d = 0; d < DIM; d += 4) {
        a0 = fmaf(p[d+0], Wv[(size_t)(d+0)*OUTER + o], a0);
        a1 = fmaf(p[d+1], Wv[(size_t)(d+1)*OUTER + o], a1);
        a2 = fmaf(p[d+2], Wv[(size_t)(d+2)*OUTER + o], a2);
        a3 = fmaf(p[d+3], Wv[(size_t)(d+3)*OUTER + o], a3);
    }
    out[(size_t)r * OUTER + o] = (a0+a1)+(a2+a3);
}

// ---------------------------------------------------------------------------
extern "C" void kernel_launch(void* const* d_in, const int* in_sizes, int n_in,
                              void* d_out, int out_size, void* d_ws, size_t ws_size,
                              hipStream_t stream)
{
    (void)in_sizes; (void)n_in; (void)out_size;
    const float* a_pad = (const float*)d_in[0];
    const float* b_pad = (const float*)d_in[1];
    const int*   len_a = (const int*)d_in[2];
    const int*   len_b = (const int*)d_in[3];
    const float* Wq    = (const float*)d_in[4];
    const float* bq    = (const float*)d_in[5];
    const float* Wk    = (const float*)d_in[6];
    const float* bk    = (const float*)d_in[7];
    const float* Wv    = (const float*)d_in[8];
    const float* bv    = (const float*)d_in[9];
    float* out = (float*)d_out;

    char* ws = (char*)d_ws;
    size_t off = 0;
    auto alloc = [&](size_t bytes) -> void* {
        void* p = (void*)(ws + off);
        off += (bytes + 255) & ~(size_t)255;
        return p;
    };

    const size_t QE = (size_t)BATCH * L * QKW;
    unsigned short* Wt  = (unsigned short*)alloc((size_t)QKW * DIM * 2);
    unsigned short* QKa = (unsigned short*)alloc(QE * 2);
    unsigned short* QKb = (unsigned short*)alloc(QE * 2);
    float* l2     = (float*)alloc((size_t)2 * BATCH * L * 4);
    float* w2     = (float*)alloc((size_t)2 * BATCH * L * 4);
    float* pooled = (float*)alloc((size_t)2 * BATCH * DIM * 4);
    unsigned short* E = (unsigned short*)(ws + off);
    size_t eAvail = (ws_size > off) ? (ws_size - off) : 0;
    int gb = (int)(eAvail / ((size_t)L * L * 2));
    if (gb < 1) gb = 1;
    if (gb > BATCH) gb = BATCH;

    wt_kernel<<<(QKW * DIM + 255) / 256, 256, 0, stream>>>(Wq, Wk, Wt);

    projqk_kernel<<<2048, 512, 0, stream>>>(a_pad, Wt, bq, bk, len_a, QKa);
    projqk_kernel<<<2048, 512, 0, stream>>>(b_pad, Wt, bq, bk, len_b, QKb);

    hipMemsetAsync(l2,     0, (size_t)2 * BATCH * L * 4,   stream);
    hipMemsetAsync(w2,     0, (size_t)2 * BATCH * L * 4,   stream);
    hipMemsetAsync(pooled, 0, (size_t)2 * BATCH * DIM * 4, stream);

    for (int dir = 0; dir < 2; ++dir) {
        const unsigned short* QKq = (dir == 0) ? QKa : QKb;
        const unsigned short* QKk = (dir == 0) ? QKb : QKa;
        const int* lenq = (dir == 0) ? len_a : len_b;
        const int* lenk = (dir == 0) ? len_b : len_a;
        float* lsum = l2 + (size_t)dir * BATCH * L;
        float* wv   = w2 + (size_t)dir * BATCH * L;
        for (int b0 = 0; b0 < BATCH; b0 += gb) {
            int g = (gb < BATCH - b0) ? gb : (BATCH - b0);
            scores_kernel<<<dim3(8, 8, g), 512, 0, stream>>>(QKq, QKk, lenq, lenk, E, lsum, b0);
            colsum_kernel<<<dim3(8, g), 256, 0, stream>>>(E, lsum, lenq, lenk, wv, b0);
        }
    }

    pool_kernel<<<dim3(8, BATCH), 256, 0, stream>>>(w2,                   b_pad, pooled);
    pool_kernel<<<dim3(8, BATCH), 256, 0, stream>>>(w2 + (size_t)BATCH*L, a_pad, pooled + (size_t)BATCH*DIM);
    outproj_kernel<<<dim3(128, 4), 256, 0, stream>>>(pooled, Wv, bv, out);
}